// Round 21
// baseline (73.422 us; speedup 1.0000x reference)
//
#include <hip/hip_runtime.h>
#include <math.h>

#define D 256
#define H 512
#define TT 10
#define THRESH 0.4f
#define KS 8          // K steps of 32 (D = 256)
#define NSPLIT 16     // scan blocks per graph

typedef __attribute__((ext_vector_type(8))) _Float16 half8;
typedef __attribute__((ext_vector_type(4))) float f32x4;

// ---------------------------------------------------------------------------
// K0: swizzle W1 [D][H] f32 -> fp16 MFMA B-fragments in ws (256 KB).
// layout (half8 = 16B units): idx = (n*8 + k)*64 + lane
//   element i = W1[k*32 + (lane>>4)*8 + i][n*16 + (lane&15)]
// n-tile n = 8 KB; 64-col chunk c (4 n-tiles) = contiguous 32 KB.
// ---------------------------------------------------------------------------
__global__ __launch_bounds__(256) void w1_prep(const float* __restrict__ W1,
                                               short* __restrict__ W1s)
{
    const int tid = blockIdx.x * 256 + threadIdx.x;   // 16384 threads
    const int lane = tid & 63;
    const int cell = tid >> 6;                        // 0..255 = (n,k)
    const int k = cell & 7;
    const int n = cell >> 3;
    const int row0 = k * 32 + (lane >> 4) * 8;
    const int col = n * 16 + (lane & 15);
    _Float16 h8[8];
    #pragma unroll
    for (int i = 0; i < 8; ++i)
        h8[i] = (_Float16)W1[(size_t)(row0 + i) * H + col];   // RTN
    *reinterpret_cast<half8*>(W1s + (((size_t)n * 8 + k) * 64 + lane) * 8) =
        *reinterpret_cast<half8*>(h8);
}

// ---------------------------------------------------------------------------
// K1 (fused): 512 blocks x 512 thr (2 blocks/CU, 4 waves/SIMD).
// Waves 0-3: R19 gate core VERBATIM (m97-class: shared 32 KB chunks,
//   2x32KB dbuf, global_load_lds, counted vmcnt(8), raw s_barrier pairs,
//   8 acc chains, 64 MFMA/barrier-pair).
// Waves 4-7: mask compaction (128 MB -> 4 MB cmask), SAME barrier schedule
//   (8 iters x 2 s_barrier), 8 groups (8 KB) per wave per iter — phase-
//   balanced with the gate's 64-MFMA compute phase.
// Per SIMD: 2 gate + 2 mask waves; setprio(1) favors the MFMA wave (T5).
// cmask layout: flat group g over B*S/256; word c bit t = mask[g*256+4t+c].
// ---------------------------------------------------------------------------
__global__ __launch_bounds__(512, 4) void gate_fused(
    const float* __restrict__ h_sub,
    const short* __restrict__ W1s,
    const float* __restrict__ b1,
    const float* __restrict__ W2,
    const float* __restrict__ b2,
    const int*   __restrict__ mask,
    float* __restrict__ submask,
    unsigned* __restrict__ gbits,                 // [S/32]
    unsigned long long* __restrict__ cmask)       // [B*S/256][4]
{
    __shared__ __align__(16) short sB[2][16384];   // 2 x 32 KB chunk buffers
    __shared__ float sb1[H], sw2[H];
    const int tid = threadIdx.x;       // 0..511
    const int lane = tid & 63;
    const int w = tid >> 6;            // wave 0..7
    const bool isGate = (w < 4);
    const int base = blockIdx.x * 128 + w * 32;    // gate waves only
    const int rot = blockIdx.x & 7;
    const float bb = b2[0];

    // gate staging helper (gate threads tid 0..255 cover 32 KB chunk)
    auto stage = [&](int cc, int b) {
        const int c = (cc + rot) & 7;
        const char* gp = (const char*)W1s + ((size_t)c << 15) + (size_t)tid * 16;
        char* lp0 = (char*)&sB[b][0] + (size_t)tid * 16;
        #pragma unroll
        for (int i = 0; i < 8; ++i) {
            __builtin_amdgcn_global_load_lds(
                (const __attribute__((address_space(1))) void*)(gp + i * 4096),
                (__attribute__((address_space(3))) void*)(lp0 + i * 4096),
                16, 0, 0);
        }
    };

    half8 af[2][KS];

    if (isGate) {
        stage(0, 0);
        stage(1, 1);
        // biases into LDS (256 gate threads x 2)
        int i = tid * 2;
        *reinterpret_cast<float2*>(&sb1[i]) = *reinterpret_cast<const float2*>(&b1[i]);
        *reinterpret_cast<float2*>(&sw2[i]) = *reinterpret_cast<const float2*>(&W2[i]);

        // A fragments fp16: 2 s-tiles x 8 k = 64 VGPR
        #pragma unroll
        for (int s = 0; s < 2; ++s) {
            const int row = base + s * 16 + (lane & 15);
            const float* rp = h_sub + (size_t)row * D + (lane >> 4) * 8;
            #pragma unroll
            for (int k = 0; k < KS; ++k) {
                float x[8];
                *reinterpret_cast<float4*>(&x[0]) =
                    *reinterpret_cast<const float4*>(rp + k * 32);
                *reinterpret_cast<float4*>(&x[4]) =
                    *reinterpret_cast<const float4*>(rp + k * 32 + 4);
                _Float16 h8[8];
                #pragma unroll
                for (int i2 = 0; i2 < 8; ++i2) h8[i2] = (_Float16)x[i2];
                af[s][k] = *reinterpret_cast<half8*>(h8);
            }
        }
    }

    // full barrier: chunks 0/1 + biases in LDS; every wave's vmem drained
    // (hipcc emits s_waitcnt vmcnt(0) lgkmcnt(0) before s_barrier)
    // -> gate waves' counted-vmcnt bookkeeping starts from zero.
    __syncthreads();

    float lp[2][4] = {{0.f,0.f,0.f,0.f},{0.f,0.f,0.f,0.f}};
    const int mw = blockIdx.x * 4 + (w - 4);       // mask-wave id (w>=4)
    const size_t g0 = (size_t)mw * 64;             // 64 groups per mask wave

    for (int cc = 0; cc < 8; ++cc) {
        if (isGate) {
            // chunk cc landed; refill for cc+1 stays in flight
            if (cc < 7) asm volatile("s_waitcnt vmcnt(8)" ::: "memory");
            else        asm volatile("s_waitcnt vmcnt(0)" ::: "memory");
            __builtin_amdgcn_s_barrier();
            __builtin_amdgcn_sched_barrier(0);

            const short* buf = &sB[cc & 1][0];
            const int c = (cc + rot) & 7;

            f32x4 acc[2][4];
            #pragma unroll
            for (int s = 0; s < 2; ++s)
                #pragma unroll
                for (int nt = 0; nt < 4; ++nt)
                    acc[s][nt] = (f32x4){0.f,0.f,0.f,0.f};

            __builtin_amdgcn_s_setprio(1);
            #pragma unroll
            for (int k = 0; k < KS; ++k) {
                half8 bh0 = *reinterpret_cast<const half8*>(buf + ((0 * 8 + k) * 64 + lane) * 8);
                half8 bh1 = *reinterpret_cast<const half8*>(buf + ((1 * 8 + k) * 64 + lane) * 8);
                half8 bh2 = *reinterpret_cast<const half8*>(buf + ((2 * 8 + k) * 64 + lane) * 8);
                half8 bh3 = *reinterpret_cast<const half8*>(buf + ((3 * 8 + k) * 64 + lane) * 8);
                acc[0][0] = __builtin_amdgcn_mfma_f32_16x16x32_f16(af[0][k], bh0, acc[0][0], 0, 0, 0);
                acc[1][0] = __builtin_amdgcn_mfma_f32_16x16x32_f16(af[1][k], bh0, acc[1][0], 0, 0, 0);
                acc[0][1] = __builtin_amdgcn_mfma_f32_16x16x32_f16(af[0][k], bh1, acc[0][1], 0, 0, 0);
                acc[1][1] = __builtin_amdgcn_mfma_f32_16x16x32_f16(af[1][k], bh1, acc[1][1], 0, 0, 0);
                acc[0][2] = __builtin_amdgcn_mfma_f32_16x16x32_f16(af[0][k], bh2, acc[0][2], 0, 0, 0);
                acc[1][2] = __builtin_amdgcn_mfma_f32_16x16x32_f16(af[1][k], bh2, acc[1][2], 0, 0, 0);
                acc[0][3] = __builtin_amdgcn_mfma_f32_16x16x32_f16(af[0][k], bh3, acc[0][3], 0, 0, 0);
                acc[1][3] = __builtin_amdgcn_mfma_f32_16x16x32_f16(af[1][k], bh3, acc[1][3], 0, 0, 0);
            }
            __builtin_amdgcn_s_setprio(0);

            #pragma unroll
            for (int nt = 0; nt < 4; ++nt) {
                const int hc = c * 64 + nt * 16 + (lane & 15);
                const float b1h = sb1[hc], w2h = sw2[hc];
                #pragma unroll
                for (int s = 0; s < 2; ++s)
                    #pragma unroll
                    for (int j = 0; j < 4; ++j) {
                        float v = acc[s][nt][j] + b1h;
                        v = v > 0.f ? v : 0.f;
                        lp[s][j] = fmaf(v, w2h, lp[s][j]);
                    }
            }

            __builtin_amdgcn_sched_barrier(0);
            __builtin_amdgcn_s_barrier();
            if (cc < 6) stage(cc + 2, cc & 1);
        } else {
            // mask waves: same 2-barrier schedule; 8 groups (8 KB) per iter
            __builtin_amdgcn_s_barrier();
            {
                const size_t gbase = g0 + (size_t)cc * 8;
                int4 m4[8];
                #pragma unroll
                for (int u = 0; u < 8; ++u)
                    m4[u] = *reinterpret_cast<const int4*>(
                        mask + (gbase + u) * 256 + (lane << 2));
                #pragma unroll
                for (int u = 0; u < 8; ++u) {
                    unsigned long long c0 = __ballot(m4[u].x != 0);
                    unsigned long long c1 = __ballot(m4[u].y != 0);
                    unsigned long long c2 = __ballot(m4[u].z != 0);
                    unsigned long long c3 = __ballot(m4[u].w != 0);
                    if (lane == 0) {
                        unsigned long long* cp = cmask + (gbase + u) * 4;
                        cp[0] = c0; cp[1] = c1; cp[2] = c2; cp[3] = c3;
                    }
                }
            }
            __builtin_amdgcn_s_barrier();
        }
    }

    if (isGate) {
        // butterfly over the 16 h-cols (low 4 lane bits)
        #pragma unroll
        for (int m = 1; m < 16; m <<= 1)
            #pragma unroll
            for (int s = 0; s < 2; ++s)
                #pragma unroll
                for (int j = 0; j < 4; ++j)
                    lp[s][j] += __shfl_xor(lp[s][j], m);

        const int g = lane >> 4;
        unsigned bits = 0;
        float sig[2][4];
        #pragma unroll
        for (int s = 0; s < 2; ++s)
            #pragma unroll
            for (int j = 0; j < 4; ++j) {
                sig[s][j] = 1.f / (1.f + expf(-(lp[s][j] + bb)));
                if (sig[s][j] > THRESH) bits |= 1u << (s * 16 + g * 4 + j);
            }
        bits |= __shfl_xor(bits, 16);
        bits |= __shfl_xor(bits, 32);
        if (lane == 0) gbits[blockIdx.x * 4 + w] = bits;

        if ((lane & 15) == 0)
            #pragma unroll
            for (int s = 0; s < 2; ++s)
                #pragma unroll
                for (int j = 0; j < 4; ++j)
                    submask[base + s * 16 + g * 4 + j] = sig[s][j];
    }
}

// ---------------------------------------------------------------------------
// K2a: gather using compact cmask (4 MB) + gbits; NSPLIT=16. (R18, proven)
// ---------------------------------------------------------------------------
__global__ __launch_bounds__(256) void seg_scan(
    const float* __restrict__ h_sub,              // [S][D]
    const unsigned long long* __restrict__ cmask, // [B*S/256][4]
    const unsigned* __restrict__ gbits,           // [S/32]
    float* __restrict__ psum,                     // [B*NSPLIT][D]
    int*   __restrict__ pcnt,                     // [B*NSPLIT]
    int S)
{
    const int i = blockIdx.x / NSPLIT;
    const int p = blockIdx.x % NSPLIT;
    const int tid = threadIdx.x;
    const int lane = tid & 63;
    const int w = tid >> 6;
    const int seg = S / NSPLIT;                 // 4096
    const int start = p * seg;
    const unsigned long long* cm =
        cmask + ((size_t)i * (S / 256) + (size_t)p * (seg / 256)) * 4;

    __shared__ unsigned sbits[4096 / 32];       // 128 words
    if (tid < seg / 32) sbits[tid] = gbits[(start >> 5) + tid];
    __syncthreads();

    float4 acc = make_float4(0.f, 0.f, 0.f, 0.f);
    int cnt = 0;

    #pragma unroll
    for (int it = 0; it < 4; ++it) {
        const int g = w * 4 + it;               // group within segment
        const int j0 = g * 256 + (lane << 2);
        const unsigned bw = sbits[j0 >> 5];
        const int sh = j0 & 31;
        unsigned long long bal[4];
        bal[0] = __ballot((bw >> (sh + 0)) & 1u) & cm[(size_t)g * 4 + 0];
        bal[1] = __ballot((bw >> (sh + 1)) & 1u) & cm[(size_t)g * 4 + 1];
        bal[2] = __ballot((bw >> (sh + 2)) & 1u) & cm[(size_t)g * 4 + 2];
        bal[3] = __ballot((bw >> (sh + 3)) & 1u) & cm[(size_t)g * 4 + 3];
        #pragma unroll
        for (int s = 0; s < 4; ++s) {
            unsigned long long b = bal[s];
            while (b) {
                int t = __builtin_ctzll(b);
                b &= b - 1;
                int jj = start + g * 256 + (t << 2) + s;
                float4 hv = *reinterpret_cast<const float4*>(
                    h_sub + (size_t)jj * D + (lane << 2));
                acc.x += hv.x; acc.y += hv.y; acc.z += hv.z; acc.w += hv.w;
                cnt++;
            }
        }
    }

    __shared__ float ssum[4][D];
    __shared__ int   scnt[4];
    *reinterpret_cast<float4*>(&ssum[w][lane << 2]) = acc;
    if (lane == 0) scnt[w] = cnt;
    __syncthreads();

    float a = ssum[0][tid] + ssum[1][tid] + ssum[2][tid] + ssum[3][tid];
    psum[(size_t)blockIdx.x * D + tid] = a;
    if (tid == 0) pcnt[blockIdx.x] = scnt[0] + scnt[1] + scnt[2] + scnt[3];
}

// ---------------------------------------------------------------------------
// K2b: combine partials -> mean, cosine, classifier logits
// ---------------------------------------------------------------------------
__global__ __launch_bounds__(256) void seg_combine(
    const float* __restrict__ h_graph,  // [B][D]
    const float* __restrict__ psum,     // [B*NSPLIT][D]
    const int*   __restrict__ pcnt,     // [B*NSPLIT]
    const float* __restrict__ Wc,       // [2D][TT]
    const float* __restrict__ bc,       // [TT]
    float* __restrict__ logits,         // [B][TT]
    float* __restrict__ cos_ws)         // [B]
{
    const int i = blockIdx.x;
    const int tid = threadIdx.x;
    const int lane = tid & 63;
    const int w = tid >> 6;

    float a = 0.f;
    int c = 0;
    #pragma unroll
    for (int p = 0; p < NSPLIT; ++p) {
        a += psum[((size_t)i * NSPLIT + p) * D + tid];
        c += pcnt[i * NSPLIT + p];
    }
    a = (c > 0) ? (a / (float)c) : 0.f;
    const float g = h_graph[(size_t)i * D + tid];

    float r0 = a * a, r1 = g * g, r2 = a * g;
    #pragma unroll
    for (int m = 1; m < 64; m <<= 1) {
        r0 += __shfl_xor(r0, m);
        r1 += __shfl_xor(r1, m);
        r2 += __shfl_xor(r2, m);
    }
    __shared__ float red[4][3];
    if (lane == 0) { red[w][0] = r0; red[w][1] = r1; red[w][2] = r2; }
    __syncthreads();
    if (tid == 0) {
        float a2 = red[0][0] + red[1][0] + red[2][0] + red[3][0];
        float g2 = red[0][1] + red[1][1] + red[2][1] + red[3][1];
        float ag = red[0][2] + red[1][2] + red[2][2] + red[3][2];
        float an = sqrtf(a2), gn = sqrtf(g2);
        float cs = (c > 0) ? (ag / (fmaxf(an, 1e-12f) * fmaxf(gn, 1e-12f))) : 0.f;
        cos_ws[i] = cs;
    }

    float lg[TT];
    #pragma unroll
    for (int t = 0; t < TT; ++t)
        lg[t] = g * Wc[(size_t)tid * TT + t] + a * Wc[(size_t)(D + tid) * TT + t];
    #pragma unroll
    for (int m = 1; m < 64; m <<= 1)
        #pragma unroll
        for (int t = 0; t < TT; ++t) lg[t] += __shfl_xor(lg[t], m);
    __shared__ float lpart[4][TT];
    if (lane == 0)
        #pragma unroll
        for (int t = 0; t < TT; ++t) lpart[w][t] = lg[t];
    __syncthreads();
    if (tid < TT)
        logits[(size_t)i * TT + tid] =
            lpart[0][tid] + lpart[1][tid] + lpart[2][tid] + lpart[3][tid] + bc[tid];
}

// ---------------------------------------------------------------------------
__global__ void loss_kernel(const float* __restrict__ cos_ws,
                            float* __restrict__ out, int B)
{
    const int lane = threadIdx.x;
    float s = 0.f;
    for (int i = lane; i < B; i += 64) s += cos_ws[i];
    #pragma unroll
    for (int m = 1; m < 64; m <<= 1) s += __shfl_xor(s, m);
    if (lane == 0) out[0] = 1.0f - s / (float)B;
}

// ---------------------------------------------------------------------------
extern "C" void kernel_launch(void* const* d_in, const int* in_sizes, int n_in,
                              void* d_out, int out_size, void* d_ws, size_t ws_size,
                              hipStream_t stream)
{
    const float* h_graph = (const float*)d_in[0];
    const float* h_sub   = (const float*)d_in[1];
    const float* W1      = (const float*)d_in[2];
    const float* b1      = (const float*)d_in[3];
    const float* W2      = (const float*)d_in[4];
    const float* b2      = (const float*)d_in[5];
    const float* Wc      = (const float*)d_in[6];
    const float* bc      = (const float*)d_in[7];
    const int*   mask    = (const int*)d_in[8];

    const int B = in_sizes[0] / D;
    const int S = in_sizes[1] / D;

    float* out     = (float*)d_out;
    float* logits  = out;                       // [B*TT]
    float* loss    = out + (size_t)B * TT;      // [1]
    float* submask = loss + 1;                  // [S]

    char* ws = (char*)d_ws;
    short*    W1s    = (short*)ws;                       // 256 KB fp16 frags
    unsigned* gbits  = (unsigned*)(ws + 512 * 1024);     // 8 KB
    int*      pcnt   = (int*)(ws + 528 * 1024);          // 32 KB
    float*    cos_ws = (float*)(ws + 576 * 1024);        // 2 KB
    float*    psum   = (float*)(ws + 1024 * 1024);       // 8 MB
    unsigned long long* cmask =
        (unsigned long long*)(ws + 16 * 1024 * 1024);    // 4 MB

    w1_prep<<<64, 256, 0, stream>>>(W1, W1s);
    gate_fused<<<S / 128, 512, 0, stream>>>(
        h_sub, W1s, b1, W2, b2, mask, submask, gbits, cmask);
    seg_scan<<<B * NSPLIT, 256, 0, stream>>>(h_sub, cmask, gbits, psum, pcnt, S);
    seg_combine<<<B, 256, 0, stream>>>(h_graph, psum, pcnt, Wc, bc, logits, cos_ws);
    loss_kernel<<<1, 64, 0, stream>>>(cos_ws, loss, B);
}

// Round 22
// 67.804 us; speedup vs baseline: 1.0829x; 1.0829x over previous
//
#include <hip/hip_runtime.h>
#include <math.h>

#define D 256
#define H 512
#define TT 10
#define THRESH 0.4f
#define KS 8          // K steps of 32 (D = 256)
#define NSPLIT 16     // scan blocks per graph
#define NGB 512       // gate blocks (blocks >= NGB do mask compaction)

typedef __attribute__((ext_vector_type(8))) _Float16 half8;
typedef __attribute__((ext_vector_type(4))) float f32x4;

// ---------------------------------------------------------------------------
// K0: swizzle W1 [D][H] f32 -> fp16 MFMA B-fragments in ws (256 KB).
// layout (half8 = 16B units): idx = (n*8 + k)*64 + lane
//   element i = W1[k*32 + (lane>>4)*8 + i][n*16 + (lane&15)]
// n-tile n = 8 KB; 32-col chunk c (2 n-tiles) = contiguous 16 KB.
// ---------------------------------------------------------------------------
__global__ __launch_bounds__(256) void w1_prep(const float* __restrict__ W1,
                                               short* __restrict__ W1s)
{
    const int tid = blockIdx.x * 256 + threadIdx.x;   // 16384 threads
    const int lane = tid & 63;
    const int cell = tid >> 6;                        // 0..255 = (n,k)
    const int k = cell & 7;
    const int n = cell >> 3;
    const int row0 = k * 32 + (lane >> 4) * 8;
    const int col = n * 16 + (lane & 15);
    _Float16 h8[8];
    #pragma unroll
    for (int i = 0; i < 8; ++i)
        h8[i] = (_Float16)W1[(size_t)(row0 + i) * H + col];   // RTN
    *reinterpret_cast<half8*>(W1s + (((size_t)n * 8 + k) * 64 + lane) * 8) =
        *reinterpret_cast<half8*>(h8);
}

// ---------------------------------------------------------------------------
// K1 (heterogeneous GRID): 1536 blocks x 256 thr.
// Blocks 0..511: R20 gate core VERBATIM (m97-class, 16 KB shared chunks,
//   2x16KB dbuf, global_load_lds, counted vmcnt(4), raw s_barrier pairs,
//   4 acc chains/wave, 36.5 KB LDS -> 4 blocks/CU).
// Blocks 512..1535: mask compaction (128 MB int32 -> 4 MB cmask ballot
//   bitmask), barrier-free, 8 int4 in flight per wave.
// Co-residency: ~2 gate + ~2 mask blocks per CU -> per SIMD 2 MFMA-heavy +
// 2 BW-heavy waves, ZERO cross-coupling (barriers & LDS are block-local).
// cmask: flat group g over B*S/256; word c bit t = (mask[g*256+4t+c] != 0).
// ---------------------------------------------------------------------------
__global__ __launch_bounds__(256, 4) void gate_fused(
    const float* __restrict__ h_sub,
    const short* __restrict__ W1s,
    const float* __restrict__ b1,
    const float* __restrict__ W2,
    const float* __restrict__ b2,
    const int*   __restrict__ mask,
    float* __restrict__ submask,
    unsigned* __restrict__ gbits,                 // [S/32]
    unsigned long long* __restrict__ cmask)       // [B*S/256][4]
{
    __shared__ __align__(16) short sB[2][8192];    // 2 x 16 KB chunk buffers
    __shared__ float sb1[H], sw2[H];
    const int tid = threadIdx.x;       // 0..255
    const int lane = tid & 63;
    const int w = tid >> 6;            // wave 0..3

    if (blockIdx.x >= NGB) {
        // ================= mask-compaction block (barrier-free) ==========
        const int mb = blockIdx.x - NGB;           // 0..1023
        const int mw = mb * 4 + w;                 // 0..4095
        const size_t g0 = (size_t)mw * 32;         // 32 groups (32 KB) / wave
        for (int it = 0; it < 4; ++it) {
            int4 m4[8];
            #pragma unroll
            for (int u = 0; u < 8; ++u)
                m4[u] = *reinterpret_cast<const int4*>(
                    mask + (g0 + it * 8 + u) * 256 + (lane << 2));
            #pragma unroll
            for (int u = 0; u < 8; ++u) {
                unsigned long long c0 = __ballot(m4[u].x != 0);
                unsigned long long c1 = __ballot(m4[u].y != 0);
                unsigned long long c2 = __ballot(m4[u].z != 0);
                unsigned long long c3 = __ballot(m4[u].w != 0);
                if (lane == 0) {
                    unsigned long long* cp = cmask + (g0 + it * 8 + u) * 4;
                    cp[0] = c0; cp[1] = c1; cp[2] = c2; cp[3] = c3;
                }
            }
        }
        return;
    }

    // ==================== gate block (R20 core verbatim) =================
    const int base = blockIdx.x * 128 + w * 32;
    const int rot = blockIdx.x & 15;   // per-block chunk rotation (L2 spread)
    const float bb = b2[0];

    auto stage = [&](int cc, int b) {
        const int c = (cc + rot) & 15;
        const char* gp = (const char*)W1s + ((size_t)c << 14) + (size_t)tid * 16;
        char* lp0 = (char*)&sB[b][0] + (size_t)tid * 16;
        #pragma unroll
        for (int i = 0; i < 4; ++i) {
            __builtin_amdgcn_global_load_lds(
                (const __attribute__((address_space(1))) void*)(gp + i * 4096),
                (__attribute__((address_space(3))) void*)(lp0 + i * 4096),
                16, 0, 0);
        }
    };

    stage(0, 0);
    stage(1, 1);

    {
        int i = tid * 2;
        *reinterpret_cast<float2*>(&sb1[i]) = *reinterpret_cast<const float2*>(&b1[i]);
        *reinterpret_cast<float2*>(&sw2[i]) = *reinterpret_cast<const float2*>(&W2[i]);
    }

    // A fragments fp16: 2 s-tiles x 8 k = 64 VGPR
    half8 af[2][KS];
    #pragma unroll
    for (int s = 0; s < 2; ++s) {
        const int row = base + s * 16 + (lane & 15);
        const float* rp = h_sub + (size_t)row * D + (lane >> 4) * 8;
        #pragma unroll
        for (int k = 0; k < KS; ++k) {
            float x[8];
            *reinterpret_cast<float4*>(&x[0]) =
                *reinterpret_cast<const float4*>(rp + k * 32);
            *reinterpret_cast<float4*>(&x[4]) =
                *reinterpret_cast<const float4*>(rp + k * 32 + 4);
            _Float16 h8[8];
            #pragma unroll
            for (int i = 0; i < 8; ++i) h8[i] = (_Float16)x[i];
            af[s][k] = *reinterpret_cast<half8*>(h8);
        }
    }

    // full barrier: biases + chunks 0/1 in LDS, ALL vmem drained
    __syncthreads();

    float lp[2][4] = {{0.f,0.f,0.f,0.f},{0.f,0.f,0.f,0.f}};

    for (int cc = 0; cc < 16; ++cc) {
        if (cc < 15) asm volatile("s_waitcnt vmcnt(4)" ::: "memory");
        else         asm volatile("s_waitcnt vmcnt(0)" ::: "memory");
        __builtin_amdgcn_s_barrier();
        __builtin_amdgcn_sched_barrier(0);

        const short* buf = &sB[cc & 1][0];
        const int c = (cc + rot) & 15;

        f32x4 acc[2][2];
        #pragma unroll
        for (int s = 0; s < 2; ++s)
            #pragma unroll
            for (int nt = 0; nt < 2; ++nt)
                acc[s][nt] = (f32x4){0.f,0.f,0.f,0.f};

        __builtin_amdgcn_s_setprio(1);
        #pragma unroll
        for (int k = 0; k < KS; ++k) {
            half8 bh0 = *reinterpret_cast<const half8*>(buf + ((0 * 8 + k) * 64 + lane) * 8);
            half8 bh1 = *reinterpret_cast<const half8*>(buf + ((1 * 8 + k) * 64 + lane) * 8);
            acc[0][0] = __builtin_amdgcn_mfma_f32_16x16x32_f16(af[0][k], bh0, acc[0][0], 0, 0, 0);
            acc[1][0] = __builtin_amdgcn_mfma_f32_16x16x32_f16(af[1][k], bh0, acc[1][0], 0, 0, 0);
            acc[0][1] = __builtin_amdgcn_mfma_f32_16x16x32_f16(af[0][k], bh1, acc[0][1], 0, 0, 0);
            acc[1][1] = __builtin_amdgcn_mfma_f32_16x16x32_f16(af[1][k], bh1, acc[1][1], 0, 0, 0);
        }
        __builtin_amdgcn_s_setprio(0);

        #pragma unroll
        for (int nt = 0; nt < 2; ++nt) {
            const int hc = c * 32 + nt * 16 + (lane & 15);
            const float b1h = sb1[hc], w2h = sw2[hc];
            #pragma unroll
            for (int s = 0; s < 2; ++s)
                #pragma unroll
                for (int j = 0; j < 4; ++j) {
                    float v = acc[s][nt][j] + b1h;
                    v = v > 0.f ? v : 0.f;
                    lp[s][j] = fmaf(v, w2h, lp[s][j]);
                }
        }

        __builtin_amdgcn_sched_barrier(0);
        __builtin_amdgcn_s_barrier();
        if (cc < 14) stage(cc + 2, cc & 1);
    }

    // butterfly over the 16 h-cols (low 4 lane bits)
    #pragma unroll
    for (int m = 1; m < 16; m <<= 1)
        #pragma unroll
        for (int s = 0; s < 2; ++s)
            #pragma unroll
            for (int j = 0; j < 4; ++j)
                lp[s][j] += __shfl_xor(lp[s][j], m);

    const int g = lane >> 4;
    unsigned bits = 0;
    float sig[2][4];
    #pragma unroll
    for (int s = 0; s < 2; ++s)
        #pragma unroll
        for (int j = 0; j < 4; ++j) {
            sig[s][j] = 1.f / (1.f + expf(-(lp[s][j] + bb)));
            if (sig[s][j] > THRESH) bits |= 1u << (s * 16 + g * 4 + j);
        }
    bits |= __shfl_xor(bits, 16);
    bits |= __shfl_xor(bits, 32);
    if (lane == 0) gbits[blockIdx.x * 4 + w] = bits;

    if ((lane & 15) == 0)
        #pragma unroll
        for (int s = 0; s < 2; ++s)
            #pragma unroll
            for (int j = 0; j < 4; ++j)
                submask[base + s * 16 + g * 4 + j] = sig[s][j];
}

// ---------------------------------------------------------------------------
// K2a: gather using compact cmask (4 MB) + gbits; NSPLIT=16. (proven)
// ---------------------------------------------------------------------------
__global__ __launch_bounds__(256) void seg_scan(
    const float* __restrict__ h_sub,              // [S][D]
    const unsigned long long* __restrict__ cmask, // [B*S/256][4]
    const unsigned* __restrict__ gbits,           // [S/32]
    float* __restrict__ psum,                     // [B*NSPLIT][D]
    int*   __restrict__ pcnt,                     // [B*NSPLIT]
    int S)
{
    const int i = blockIdx.x / NSPLIT;
    const int p = blockIdx.x % NSPLIT;
    const int tid = threadIdx.x;
    const int lane = tid & 63;
    const int w = tid >> 6;
    const int seg = S / NSPLIT;                 // 4096
    const int start = p * seg;
    const unsigned long long* cm =
        cmask + ((size_t)i * (S / 256) + (size_t)p * (seg / 256)) * 4;

    __shared__ unsigned sbits[4096 / 32];       // 128 words
    if (tid < seg / 32) sbits[tid] = gbits[(start >> 5) + tid];
    __syncthreads();

    float4 acc = make_float4(0.f, 0.f, 0.f, 0.f);
    int cnt = 0;

    #pragma unroll
    for (int it = 0; it < 4; ++it) {
        const int g = w * 4 + it;               // group within segment
        const int j0 = g * 256 + (lane << 2);
        const unsigned bw = sbits[j0 >> 5];
        const int sh = j0 & 31;
        unsigned long long bal[4];
        bal[0] = __ballot((bw >> (sh + 0)) & 1u) & cm[(size_t)g * 4 + 0];
        bal[1] = __ballot((bw >> (sh + 1)) & 1u) & cm[(size_t)g * 4 + 1];
        bal[2] = __ballot((bw >> (sh + 2)) & 1u) & cm[(size_t)g * 4 + 2];
        bal[3] = __ballot((bw >> (sh + 3)) & 1u) & cm[(size_t)g * 4 + 3];
        #pragma unroll
        for (int s = 0; s < 4; ++s) {
            unsigned long long b = bal[s];
            while (b) {
                int t = __builtin_ctzll(b);
                b &= b - 1;
                int jj = start + g * 256 + (t << 2) + s;
                float4 hv = *reinterpret_cast<const float4*>(
                    h_sub + (size_t)jj * D + (lane << 2));
                acc.x += hv.x; acc.y += hv.y; acc.z += hv.z; acc.w += hv.w;
                cnt++;
            }
        }
    }

    __shared__ float ssum[4][D];
    __shared__ int   scnt[4];
    *reinterpret_cast<float4*>(&ssum[w][lane << 2]) = acc;
    if (lane == 0) scnt[w] = cnt;
    __syncthreads();

    float a = ssum[0][tid] + ssum[1][tid] + ssum[2][tid] + ssum[3][tid];
    psum[(size_t)blockIdx.x * D + tid] = a;
    if (tid == 0) pcnt[blockIdx.x] = scnt[0] + scnt[1] + scnt[2] + scnt[3];
}

// ---------------------------------------------------------------------------
// K2b: combine partials -> mean, cosine, classifier logits
// ---------------------------------------------------------------------------
__global__ __launch_bounds__(256) void seg_combine(
    const float* __restrict__ h_graph,  // [B][D]
    const float* __restrict__ psum,     // [B*NSPLIT][D]
    const int*   __restrict__ pcnt,     // [B*NSPLIT]
    const float* __restrict__ Wc,       // [2D][TT]
    const float* __restrict__ bc,       // [TT]
    float* __restrict__ logits,         // [B][TT]
    float* __restrict__ cos_ws)         // [B]
{
    const int i = blockIdx.x;
    const int tid = threadIdx.x;
    const int lane = tid & 63;
    const int w = tid >> 6;

    float a = 0.f;
    int c = 0;
    #pragma unroll
    for (int p = 0; p < NSPLIT; ++p) {
        a += psum[((size_t)i * NSPLIT + p) * D + tid];
        c += pcnt[i * NSPLIT + p];
    }
    a = (c > 0) ? (a / (float)c) : 0.f;
    const float g = h_graph[(size_t)i * D + tid];

    float r0 = a * a, r1 = g * g, r2 = a * g;
    #pragma unroll
    for (int m = 1; m < 64; m <<= 1) {
        r0 += __shfl_xor(r0, m);
        r1 += __shfl_xor(r1, m);
        r2 += __shfl_xor(r2, m);
    }
    __shared__ float red[4][3];
    if (lane == 0) { red[w][0] = r0; red[w][1] = r1; red[w][2] = r2; }
    __syncthreads();
    if (tid == 0) {
        float a2 = red[0][0] + red[1][0] + red[2][0] + red[3][0];
        float g2 = red[0][1] + red[1][1] + red[2][1] + red[3][1];
        float ag = red[0][2] + red[1][2] + red[2][2] + red[3][2];
        float an = sqrtf(a2), gn = sqrtf(g2);
        float cs = (c > 0) ? (ag / (fmaxf(an, 1e-12f) * fmaxf(gn, 1e-12f))) : 0.f;
        cos_ws[i] = cs;
    }

    float lg[TT];
    #pragma unroll
    for (int t = 0; t < TT; ++t)
        lg[t] = g * Wc[(size_t)tid * TT + t] + a * Wc[(size_t)(D + tid) * TT + t];
    #pragma unroll
    for (int m = 1; m < 64; m <<= 1)
        #pragma unroll
        for (int t = 0; t < TT; ++t) lg[t] += __shfl_xor(lg[t], m);
    __shared__ float lpart[4][TT];
    if (lane == 0)
        #pragma unroll
        for (int t = 0; t < TT; ++t) lpart[w][t] = lg[t];
    __syncthreads();
    if (tid < TT)
        logits[(size_t)i * TT + tid] =
            lpart[0][tid] + lpart[1][tid] + lpart[2][tid] + lpart[3][tid] + bc[tid];
}

// ---------------------------------------------------------------------------
__global__ void loss_kernel(const float* __restrict__ cos_ws,
                            float* __restrict__ out, int B)
{
    const int lane = threadIdx.x;
    float s = 0.f;
    for (int i = lane; i < B; i += 64) s += cos_ws[i];
    #pragma unroll
    for (int m = 1; m < 64; m <<= 1) s += __shfl_xor(s, m);
    if (lane == 0) out[0] = 1.0f - s / (float)B;
}

// ---------------------------------------------------------------------------
extern "C" void kernel_launch(void* const* d_in, const int* in_sizes, int n_in,
                              void* d_out, int out_size, void* d_ws, size_t ws_size,
                              hipStream_t stream)
{
    const float* h_graph = (const float*)d_in[0];
    const float* h_sub   = (const float*)d_in[1];
    const float* W1      = (const float*)d_in[2];
    const float* b1      = (const float*)d_in[3];
    const float* W2      = (const float*)d_in[4];
    const float* b2      = (const float*)d_in[5];
    const float* Wc      = (const float*)d_in[6];
    const float* bc      = (const float*)d_in[7];
    const int*   mask    = (const int*)d_in[8];

    const int B = in_sizes[0] / D;
    const int S = in_sizes[1] / D;

    float* out     = (float*)d_out;
    float* logits  = out;                       // [B*TT]
    float* loss    = out + (size_t)B * TT;      // [1]
    float* submask = loss + 1;                  // [S]

    char* ws = (char*)d_ws;
    short*    W1s    = (short*)ws;                       // 256 KB fp16 frags
    unsigned* gbits  = (unsigned*)(ws + 512 * 1024);     // 8 KB
    int*      pcnt   = (int*)(ws + 528 * 1024);          // 32 KB
    float*    cos_ws = (float*)(ws + 576 * 1024);        // 2 KB
    float*    psum   = (float*)(ws + 1024 * 1024);       // 8 MB
    unsigned long long* cmask =
        (unsigned long long*)(ws + 16 * 1024 * 1024);    // 4 MB

    const int nMaskBlocks = (B * (S / 256)) / 128;       // 1024
    w1_prep<<<64, 256, 0, stream>>>(W1, W1s);
    gate_fused<<<NGB + nMaskBlocks, 256, 0, stream>>>(
        h_sub, W1s, b1, W2, b2, mask, submask, gbits, cmask);
    seg_scan<<<B * NSPLIT, 256, 0, stream>>>(h_sub, cmask, gbits, psum, pcnt, S);
    seg_combine<<<B, 256, 0, stream>>>(h_graph, psum, pcnt, Wc, bc, logits, cos_ws);
    loss_kernel<<<1, 64, 0, stream>>>(cos_ws, loss, B);
}